// Round 5
// baseline (397.489 us; speedup 1.0000x reference)
//
#include <hip/hip_runtime.h>
#include <hip/hip_bf16.h>
#include <cstdint>

// Problem constants
#define NROWS   131072
#define NUNITS  256
#define KTOT    512          // INPUT_DIM + UNITS
#define BM      64
#define THREADS 512

typedef float f32x4  __attribute__((ext_vector_type(4)));
typedef short bf16x8 __attribute__((ext_vector_type(8)));

__device__ __forceinline__ short f2bf(float x) {
    unsigned u = __float_as_uint(x);
    u += 0x7FFFu + ((u >> 16) & 1u);   // round-to-nearest-even
    return (short)(u >> 16);
}
__device__ __forceinline__ unsigned pack2(float lo, float hi) {
    return ((unsigned)(unsigned short)f2bf(hi) << 16) | (unsigned short)f2bf(lo);
}

// Raw barrier: drain only LDS ops; global prefetch loads stay in flight.
#define BAR() do { asm volatile("s_waitcnt lgkmcnt(0)" ::: "memory"); \
                   __builtin_amdgcn_s_barrier(); } while (0)

// W [512][1024] fp32  ->  Wws [16][1024][32] bf16 (B-fragment order, L2-resident)
__global__ void convert_W_kernel(const float* __restrict__ W, short* __restrict__ Wws) {
    int i = blockIdx.x * 256 + threadIdx.x;       // 0 .. 524287
    int k = i >> 10;
    int c = i & 1023;
    Wws[((size_t)(k >> 5) << 15) + ((size_t)c << 5) + (k & 31)] = f2bf(W[i]);
}

// Grid 4096 = 2048 row-tiles x 2 col-halves, XCD-swizzled.
// 8 phases of BK=64: 32 MFMAs/wave/barrier. A-tile 64x64 bf16, double-buffered,
// XOR-swizzled 16B granules (2-way max = free). A global loads issued 2 phases
// ahead (HBM ~900cyc covered); B (L2-resident) rolls through 3 register sets.
__global__ void __launch_bounds__(THREADS, 3)
lstm_main_kernel(const float* __restrict__ x, const float* __restrict__ h_prev,
                 const float* __restrict__ c_prev, const float* __restrict__ bias,
                 const float* __restrict__ pi, const float* __restrict__ pf,
                 const float* __restrict__ po, const short* __restrict__ Wws,
                 float* __restrict__ out) {
    __shared__ short Alds[2][BM * 64];   // 2 x 8 KiB

    // XCD-aware bijective swizzle: ch-pair lands adjacent on the same XCD.
    const int bid = blockIdx.x;
    const int swz = (bid & 7) * 512 + (bid >> 3);
    const int rt  = swz >> 1;
    const int ch  = swz & 1;
    const int row0 = rt * BM;

    const int t    = threadIdx.x;
    const int lane = t & 63;
    const int w    = t >> 6;
    const int lr   = lane & 15;
    const int hi   = lane >> 4;          // k-granule within fragment

    // ---- staging: thread -> one 16B granule (8 k) of the 64x64 A tile ----
    const int srow = t >> 3;             // 0..63
    const int sg   = t & 7;              // granule 0..7
    const int s_lds = srow * 64 + ((sg ^ (srow & 7)) * 8);     // shorts
    const float* aRowX = x      + (size_t)(row0 + srow) * 256 + sg * 8;
    const float* aRowH = h_prev + (size_t)(row0 + srow) * 256 + sg * 8;

    // ---- B-fragment base: col = g*256 + ch*128 + w*16 + lr ----
    const int ucol = ch * 128 + w * 16 + lr;
    const short* wbase = Wws + ((size_t)ucol << 5) + hi * 8;   // + ks*32768 + g*8192

    f32x4 acc[4][4];
    #pragma unroll
    for (int m = 0; m < 4; ++m)
        #pragma unroll
        for (int g = 0; g < 4; ++g)
            acc[m][g] = (f32x4){0.f, 0.f, 0.f, 0.f};

    bf16x8 BA[4], BB[4], BC[4];
    float4 sE[2], sO[2];                 // A in-flight slots (even/odd phase)

    auto loadBset = [&](int ks, bf16x8* B) {
        const short* wk = wbase + ((size_t)ks << 15);
        #pragma unroll
        for (int g = 0; g < 4; ++g)
            B[g] = *(const bf16x8*)(wk + g * 8192);
    };
    auto loadA2 = [&](int p, float4* s) {
        const float* base = (p < 4 ? aRowX : aRowH) + (p & 3) * 64;
        s[0] = *(const float4*)base;
        s[1] = *(const float4*)(base + 4);
    };
    auto writeA = [&](const float4* s, int buf) {
        int4 v;
        v.x = pack2(s[0].x, s[0].y);
        v.y = pack2(s[0].z, s[0].w);
        v.z = pack2(s[1].x, s[1].y);
        v.w = pack2(s[1].z, s[1].w);
        *(int4*)&Alds[buf][s_lds] = v;
    };
    auto mfmaHalf = [&](const bf16x8* B, int buf, int kk) {
        bf16x8 af[4];
        #pragma unroll
        for (int m = 0; m < 4; ++m)
            af[m] = *(const bf16x8*)&Alds[buf][(m * 16 + lr) * 64
                                              + (((kk * 4 + hi) ^ (lr & 7)) * 8)];
        #pragma unroll
        for (int g = 0; g < 4; ++g)
            #pragma unroll
            for (int m = 0; m < 4; ++m)
                acc[m][g] = __builtin_amdgcn_mfma_f32_16x16x32_bf16(af[m], B[g], acc[m][g], 0, 0, 0);
    };

    // ---- prologue: A(0),A(1) in flight; B(ks=0); publish A(0) ----
    loadA2(0, sE);
    loadA2(1, sO);
    loadBset(0, BA);
    writeA(sE, 0);
    BAR();

    // ---- 8 phases (BK=64), unrolled in even/odd pairs ----
    #pragma unroll 1
    for (int p2 = 0; p2 < 4; ++p2) {
        const int pe = 2 * p2;
        {   // even phase pe: reads buf0 with BA(ks=2pe) + BB(ks=2pe+1)
            loadBset(2 * pe + 1, BB);
            if (pe < 7) loadBset(2 * pe + 2, BC);
            if (pe < 6) loadA2(pe + 2, sE);
            mfmaHalf(BA, 0, 0);
            mfmaHalf(BB, 0, 1);
            writeA(sO, 1);               // publish A(pe+1)
            BAR();
        }
        const int po = pe + 1;
        {   // odd phase po: reads buf1 with BC(ks=2po) + BB(ks=2po+1)
            loadBset(2 * po + 1, BB);
            if (po < 7) loadBset(2 * po + 2, BA);
            if (po < 6) loadA2(po + 2, sO);
            mfmaHalf(BC, 1, 0);
            mfmaHalf(BB, 1, 1);
            if (po < 7) {
                writeA(sE, 0);           // publish A(po+1)
                BAR();
            }
        }
    }

    // ---- fused LSTM epilogue (lane-local: all 4 gates in acc[m][0..3]) ----
    const size_t HS = (size_t)NROWS * NUNITS;
    const int u = ucol;
    const float bi = bias[u],       bfg = bias[256 + u];
    const float bc = bias[512 + u], bo  = bias[768 + u];
    const float ppi = pi[u], ppf = pf[u], ppo = po[u];
    #pragma unroll
    for (int m = 0; m < 4; ++m) {
        #pragma unroll
        for (int r = 0; r < 4; ++r) {
            const int row = row0 + m * 16 + hi * 4 + r;
            const size_t o = (size_t)row * NUNITS + u;
            const float cp = c_prev[o];
            float zi = acc[m][0][r] + bi  + ppi * cp;
            float zf = acc[m][1][r] + bfg + ppf * cp;
            float zc = acc[m][2][r] + bc;
            float zo = acc[m][3][r] + bo  + ppo * cp;
            float ig = 1.f / (1.f + __expf(-zi));
            float fg = 1.f / (1.f + __expf(-zf));
            float og = 1.f / (1.f + __expf(-zo));
            zc = fminf(fmaxf(zc, -30.f), 30.f);
            float e2 = __expf(2.f * zc);
            float chat = (e2 - 1.f) / (e2 + 1.f);
            float c  = fg * cp + ig * chat;
            float ccl = fminf(fmaxf(c, -30.f), 30.f);
            float e3 = __expf(2.f * ccl);
            float th = (e3 - 1.f) / (e3 + 1.f);
            float h  = og * th;
            out[o]          = h;
            out[HS + o]     = h;
            out[2 * HS + o] = c;
        }
    }
}

extern "C" void kernel_launch(void* const* d_in, const int* in_sizes, int n_in,
                              void* d_out, int out_size, void* d_ws, size_t ws_size,
                              hipStream_t stream) {
    const float* x  = (const float*)d_in[0];
    const float* h  = (const float*)d_in[1];
    const float* c  = (const float*)d_in[2];
    const float* W  = (const float*)d_in[3];
    const float* b  = (const float*)d_in[4];
    const float* pi = (const float*)d_in[5];
    const float* pf = (const float*)d_in[6];
    const float* po = (const float*)d_in[7];
    short* Wws = (short*)d_ws;            // 1 MiB bf16 copy of W in B-frag order
    float* out = (float*)d_out;

    hipLaunchKernelGGL(convert_W_kernel, dim3(2048), dim3(256), 0, stream, W, Wws);
    hipLaunchKernelGGL(lstm_main_kernel, dim3(2 * NROWS / BM), dim3(THREADS), 0, stream,
                       x, h, c, b, pi, pf, po, Wws, out);
}

// Round 6
// 322.058 us; speedup vs baseline: 1.2342x; 1.2342x over previous
//
#include <hip/hip_runtime.h>
#include <cstdint>

// Problem constants
#define NROWS   131072
#define NUNITS  256
#define KTOT    512          // INPUT_DIM + UNITS
#define BM      128          // rows per block
#define THREADS 512

typedef float f32x4  __attribute__((ext_vector_type(4)));
typedef short bf16x8 __attribute__((ext_vector_type(8)));

__device__ __forceinline__ short f2bf(float x) {
    unsigned u = __float_as_uint(x);
    u += 0x7FFFu + ((u >> 16) & 1u);   // round-to-nearest-even
    return (short)(u >> 16);
}

// Fused prepass: blocks [0,32768) convert x|h -> Aws bf16 [row][512];
// blocks [32768,34816) convert W fp32 [512][1024] -> Wws [16][1024][32] bf16
// (per-K32-step, column-major, 32 contiguous k per col = B-frag order).
__global__ void convert_kernel(const float* __restrict__ x, const float* __restrict__ h,
                               const float* __restrict__ W,
                               short* __restrict__ Aws, short* __restrict__ Wws) {
    int b = blockIdx.x;
    if (b < 32768) {
        int i = b * 256 + threadIdx.x;       // 0 .. 8388607
        int row = i >> 6;
        int c   = (i & 63) * 4;
        float4 xv = *(const float4*)(x + (size_t)row * 256 + c);
        float4 hv = *(const float4*)(h + (size_t)row * 256 + c);
        short xs[4] = {f2bf(xv.x), f2bf(xv.y), f2bf(xv.z), f2bf(xv.w)};
        short hs[4] = {f2bf(hv.x), f2bf(hv.y), f2bf(hv.z), f2bf(hv.w)};
        *(uint2*)(Aws + (size_t)row * 512 + c)       = *(uint2*)xs;
        *(uint2*)(Aws + (size_t)row * 512 + 256 + c) = *(uint2*)hs;
    } else {
        int i = (b - 32768) * 256 + threadIdx.x;   // 0 .. 524287
        int k = i >> 10;
        int c = i & 1023;
        Wws[((size_t)(k >> 5) << 15) + ((size_t)c << 5) + (k & 31)] = f2bf(W[i]);
    }
}

// Main (m97-structure port): grid 4096 = 1024 row-tiles x 4 u-tiles (XCD-swz).
// Block: 128 rows x 64 u-cols x 4 gates (256 output cols). 8 waves = 2 row-
// halves x 4 col-quarters; wave tile 64x64, acc[4][4] (all 4 gates lane-local).
// Per K32-step: 3x global_load_lds(16B) per thread (A 8KB + B 16KB), triple-
// buffered LDS, counted vmcnt(3) (DMAs 2 phases in flight), raw s_barrier.
// Granule XOR-swizzle baked into DMA SOURCE addresses (LDS dest linear, #21);
// frag ds_read_b128 is a bijection over each 1KB region -> conflict-free.
__global__ void __launch_bounds__(THREADS, 4)
lstm_main_kernel(const float* __restrict__ c_prev, const float* __restrict__ bias,
                 const float* __restrict__ pi, const float* __restrict__ pf,
                 const float* __restrict__ po, const short* __restrict__ Aws,
                 const short* __restrict__ Wws, float* __restrict__ out) {
    __shared__ short lds[3][12288];   // per buf: A [0,4096) shorts, B [4096,12288)

    // XCD-aware bijective swizzle (4096 % 8 == 0): the 4 u-tiles of one
    // row-panel land on the same XCD adjacent in time -> A panel L2-reused.
    const int bid = blockIdx.x;
    const int swz = (bid & 7) * 512 + (bid >> 3);
    const int ut  = swz & 3;
    const int rt  = swz >> 2;
    const int row0 = rt * BM;

    const int t    = threadIdx.x;
    const int lane = t & 63;
    const int w    = t >> 6;
    const int lr   = lane & 15;
    const int hi   = lane >> 4;          // k-granule 0..3
    const int rh   = w >> 2;             // row half 0..1
    const int q    = w & 3;              // col quarter 0..3

    // ---- per-lane DMA source addresses (granule-swizzled) ----
    const int arow = t >> 2, ags = t & 3;
    const short* srcA = Aws + (size_t)(row0 + arow) * 512 + ((ags ^ (arow & 3)) * 8);
    const int G1 = t + 512;
    const int g0 = t >> 8,  u0 = (t >> 2) & 63,  s0 = t & 3;
    const int g1 = G1 >> 8, u1 = (G1 >> 2) & 63, s1 = G1 & 3;
    const short* srcB0 = Wws + (size_t)(g0 * 256 + ut * 64 + u0) * 32 + ((s0 ^ (u0 & 3)) * 8);
    const short* srcB1 = Wws + (size_t)(g1 * 256 + ut * 64 + u1) * 32 + ((s1 ^ (u1 & 3)) * 8);

    // ---- fragment read offsets (shorts) ----
    const int sw8  = (hi ^ (lr & 3)) * 8;
    const int aoff = (rh * 64 + lr) * 32 + sw8;          // + m*512
    const int boff = 4096 + (q * 16 + lr) * 32 + sw8;    // + g*2048

    f32x4 acc[4][4];
    #pragma unroll
    for (int m = 0; m < 4; ++m)
        #pragma unroll
        for (int g = 0; g < 4; ++g)
            acc[m][g] = (f32x4){0.f, 0.f, 0.f, 0.f};

    auto issueDMA = [&](int ks, int buf) {
        short* dst = &lds[buf][0];
        __builtin_amdgcn_global_load_lds(
            (const __attribute__((address_space(1))) uint32_t*)(const void*)(srcA + ks * 32),
            (__attribute__((address_space(3))) uint32_t*)(void*)(dst + w * 512), 16, 0, 0);
        __builtin_amdgcn_global_load_lds(
            (const __attribute__((address_space(1))) uint32_t*)(const void*)(srcB0 + (size_t)ks * 32768),
            (__attribute__((address_space(3))) uint32_t*)(void*)(dst + 4096 + w * 512), 16, 0, 0);
        __builtin_amdgcn_global_load_lds(
            (const __attribute__((address_space(1))) uint32_t*)(const void*)(srcB1 + (size_t)ks * 32768),
            (__attribute__((address_space(3))) uint32_t*)(void*)(dst + 8192 + w * 512), 16, 0, 0);
    };

    auto compute = [&](int buf) {
        const short* L = &lds[buf][0];
        bf16x8 af[4], bfr[4];
        #pragma unroll
        for (int m = 0; m < 4; ++m)
            af[m] = *(const bf16x8*)&L[aoff + m * 512];
        #pragma unroll
        for (int g = 0; g < 4; ++g)
            bfr[g] = *(const bf16x8*)&L[boff + g * 2048];
        #pragma unroll
        for (int g = 0; g < 4; ++g)
            #pragma unroll
            for (int m = 0; m < 4; ++m)
                acc[m][g] = __builtin_amdgcn_mfma_f32_16x16x32_bf16(af[m], bfr[g], acc[m][g], 0, 0, 0);
    };

    // ---- prologue: DMAs for steps 0 and 1 in flight ----
    issueDMA(0, 0);
    issueDMA(1, 1);

    int cur = 0;
    #pragma unroll 1
    for (int p = 0; p < 16; ++p) {
        // wait my wave's DMA(p) (leave DMA(p+1) in flight), then sync all waves
        if (p < 15) { asm volatile("s_waitcnt vmcnt(3)" ::: "memory"); }
        else        { asm volatile("s_waitcnt vmcnt(0)" ::: "memory"); }
        __builtin_amdgcn_s_barrier();
        if (p < 14) {
            int nb = cur + 2; if (nb >= 3) nb -= 3;
            issueDMA(p + 2, nb);             // overwrites buf read 3 phases ago
        }
        compute(cur);
        if (++cur == 3) cur = 0;
    }

    // ---- fused LSTM epilogue (lane-local: all 4 gates in acc[m][0..3]) ----
    const size_t HS = (size_t)NROWS * NUNITS;
    const int u = ut * 64 + q * 16 + lr;
    const float bi = bias[u],       bfg = bias[256 + u];
    const float bc = bias[512 + u], bo  = bias[768 + u];
    const float ppi = pi[u], ppf = pf[u], ppo = po[u];
    #pragma unroll
    for (int m = 0; m < 4; ++m) {
        #pragma unroll
        for (int r = 0; r < 4; ++r) {
            const int row = row0 + rh * 64 + m * 16 + hi * 4 + r;
            const size_t o = (size_t)row * NUNITS + u;
            const float cp = c_prev[o];
            float zi = acc[m][0][r] + bi  + ppi * cp;
            float zf = acc[m][1][r] + bfg + ppf * cp;
            float zc = acc[m][2][r] + bc;
            float zo = acc[m][3][r] + bo  + ppo * cp;
            float ig = 1.f / (1.f + __expf(-zi));
            float fg = 1.f / (1.f + __expf(-zf));
            float og = 1.f / (1.f + __expf(-zo));
            zc = fminf(fmaxf(zc, -30.f), 30.f);
            float e2 = __expf(2.f * zc);
            float chat = (e2 - 1.f) / (e2 + 1.f);
            float c  = fg * cp + ig * chat;
            float ccl = fminf(fmaxf(c, -30.f), 30.f);
            float e3 = __expf(2.f * ccl);
            float th = (e3 - 1.f) / (e3 + 1.f);
            float h  = og * th;
            out[o]          = h;
            out[HS + o]     = h;
            out[2 * HS + o] = c;
        }
    }
}

extern "C" void kernel_launch(void* const* d_in, const int* in_sizes, int n_in,
                              void* d_out, int out_size, void* d_ws, size_t ws_size,
                              hipStream_t stream) {
    const float* x  = (const float*)d_in[0];
    const float* h  = (const float*)d_in[1];
    const float* c  = (const float*)d_in[2];
    const float* W  = (const float*)d_in[3];
    const float* b  = (const float*)d_in[4];
    const float* pi = (const float*)d_in[5];
    const float* pf = (const float*)d_in[6];
    const float* po = (const float*)d_in[7];
    float* out = (float*)d_out;

    const size_t aws_bytes = (size_t)NROWS * KTOT * 2;   // 134,217,728 (ws proven >= this + 1MB in R3)
    short* Aws = (short*)d_ws;
    short* Wws = (short*)((char*)d_ws + aws_bytes);

    hipLaunchKernelGGL(convert_kernel, dim3(32768 + 2048), dim3(256), 0, stream,
                       x, h, W, Aws, Wws);
    hipLaunchKernelGGL(lstm_main_kernel, dim3(NROWS / BM * 4), dim3(THREADS), 0, stream,
                       c, b, pi, pf, po, Aws, Wws, out);
}

// Round 7
// 321.732 us; speedup vs baseline: 1.2355x; 1.0010x over previous
//
#include <hip/hip_runtime.h>
#include <cstdint>

// Problem constants
#define NROWS   131072
#define NUNITS  256
#define KTOT    512          // INPUT_DIM + UNITS
#define BM      128          // rows per block
#define THREADS 512

typedef float f32x4  __attribute__((ext_vector_type(4)));
typedef short bf16x8 __attribute__((ext_vector_type(8)));

__device__ __forceinline__ short f2bf(float x) {
    unsigned u = __float_as_uint(x);
    u += 0x7FFFu + ((u >> 16) & 1u);   // round-to-nearest-even
    return (short)(u >> 16);
}

// Fused prepass: blocks [0,32768) convert x|h -> Aws bf16 [row][512];
// blocks [32768,34816) convert W fp32 [512][1024] -> Wws [16][1024][32] bf16
// (per-K32-step, column-major, 32 contiguous k per col = B-frag order).
__global__ void convert_kernel(const float* __restrict__ x, const float* __restrict__ h,
                               const float* __restrict__ W,
                               short* __restrict__ Aws, short* __restrict__ Wws) {
    int b = blockIdx.x;
    if (b < 32768) {
        int i = b * 256 + threadIdx.x;       // 0 .. 8388607
        int row = i >> 6;
        int c   = (i & 63) * 4;
        float4 xv = *(const float4*)(x + (size_t)row * 256 + c);
        float4 hv = *(const float4*)(h + (size_t)row * 256 + c);
        short xs[4] = {f2bf(xv.x), f2bf(xv.y), f2bf(xv.z), f2bf(xv.w)};
        short hs[4] = {f2bf(hv.x), f2bf(hv.y), f2bf(hv.z), f2bf(hv.w)};
        *(uint2*)(Aws + (size_t)row * 512 + c)       = *(uint2*)xs;
        *(uint2*)(Aws + (size_t)row * 512 + 256 + c) = *(uint2*)hs;
    } else {
        int i = (b - 32768) * 256 + threadIdx.x;   // 0 .. 524287
        int k = i >> 10;
        int c = i & 1023;
        Wws[((size_t)(k >> 5) << 15) + ((size_t)c << 5) + (k & 31)] = f2bf(W[i]);
    }
}

// Main (m97-structure): grid 4096 = 1024 row-tiles x 4 u-tiles (XCD-swz).
// Block: 128 rows x 64 u-cols x 4 gates. 8 waves = 2 row-halves x 4 col-
// quarters; wave tile 64x64, acc[4][4] (all 4 gates lane-local).
// Per K32-step: 3x global_load_lds(16B)/thread, triple-buffered LDS, counted
// vmcnt(3), raw s_barrier, setprio around MFMA cluster (T5).
// Granule XOR-swizzle g' = g ^ ((row>>1)&3) baked into DMA SOURCE addresses
// (LDS dest linear, rule #21); with 64B row stride this gives 2-way max
// aliasing on ds_read_b128 (free, m136) -- R2-validated scheme.
__global__ void __launch_bounds__(THREADS, 4)
lstm_main_kernel(const float* __restrict__ c_prev, const float* __restrict__ bias,
                 const float* __restrict__ pi, const float* __restrict__ pf,
                 const float* __restrict__ po, const short* __restrict__ Aws,
                 const short* __restrict__ Wws, float* __restrict__ out) {
    __shared__ short lds[3][12288];   // per buf: A [0,4096) shorts, B [4096,12288)

    // XCD-aware bijective swizzle (4096 % 8 == 0): the 4 u-tiles of one
    // row-panel land on the same XCD adjacent in time -> A panel L2-reused.
    const int bid = blockIdx.x;
    const int swz = (bid & 7) * 512 + (bid >> 3);
    const int ut  = swz & 3;
    const int rt  = swz >> 2;
    const int row0 = rt * BM;

    const int t    = threadIdx.x;
    const int lane = t & 63;
    const int w    = t >> 6;
    const int lr   = lane & 15;
    const int hi   = lane >> 4;          // k-granule 0..3
    const int rh   = w >> 2;             // row half 0..1
    const int q    = w & 3;              // col quarter 0..3

    // ---- per-lane DMA source addresses (granule-swizzled with (row>>1)&3) ----
    const int arow = t >> 2, ags = t & 3;
    const short* srcA = Aws + (size_t)(row0 + arow) * 512
                            + ((ags ^ ((arow >> 1) & 3)) * 8);
    const int g0 = t >> 8,      u0 = (t >> 2) & 63;
    const int g1 = 2 + (t >> 8);
    const int bsw = ((t & 3) ^ ((t >> 3) & 3)) * 8;      // LDS row = t>>2 (+128)
    const short* srcB0 = Wws + (size_t)(g0 * 256 + ut * 64 + u0) * 32 + bsw;
    const short* srcB1 = Wws + (size_t)(g1 * 256 + ut * 64 + u0) * 32 + bsw;

    // ---- fragment read offsets (shorts): swizzle matches write side ----
    const int sw8  = (hi ^ ((lr >> 1) & 3)) * 8;
    const int aoff = (rh * 64 + lr) * 32 + sw8;          // + m*512
    const int boff = 4096 + (q * 16 + lr) * 32 + sw8;    // + g*2048

    f32x4 acc[4][4];
    #pragma unroll
    for (int m = 0; m < 4; ++m)
        #pragma unroll
        for (int g = 0; g < 4; ++g)
            acc[m][g] = (f32x4){0.f, 0.f, 0.f, 0.f};

    auto issueDMA = [&](const short* pA, const short* pB0, const short* pB1, int buf) {
        short* dst = &lds[buf][0];
        __builtin_amdgcn_global_load_lds(
            (const __attribute__((address_space(1))) uint32_t*)(const void*)pA,
            (__attribute__((address_space(3))) uint32_t*)(void*)(dst + w * 512), 16, 0, 0);
        __builtin_amdgcn_global_load_lds(
            (const __attribute__((address_space(1))) uint32_t*)(const void*)pB0,
            (__attribute__((address_space(3))) uint32_t*)(void*)(dst + 4096 + w * 512), 16, 0, 0);
        __builtin_amdgcn_global_load_lds(
            (const __attribute__((address_space(1))) uint32_t*)(const void*)pB1,
            (__attribute__((address_space(3))) uint32_t*)(void*)(dst + 8192 + w * 512), 16, 0, 0);
    };

    auto compute = [&](int buf) {
        const short* L = &lds[buf][0];
        bf16x8 af[4], bfr[4];
        #pragma unroll
        for (int m = 0; m < 4; ++m)
            af[m] = *(const bf16x8*)&L[aoff + m * 512];
        #pragma unroll
        for (int g = 0; g < 4; ++g)
            bfr[g] = *(const bf16x8*)&L[boff + g * 2048];
        __builtin_amdgcn_s_setprio(1);
        #pragma unroll
        for (int g = 0; g < 4; ++g)
            #pragma unroll
            for (int m = 0; m < 4; ++m)
                acc[m][g] = __builtin_amdgcn_mfma_f32_16x16x32_bf16(af[m], bfr[g], acc[m][g], 0, 0, 0);
        __builtin_amdgcn_s_setprio(0);
    };

    // ---- prologue: DMAs for steps 0 and 1 in flight ----
    issueDMA(srcA,      srcB0,         srcB1,         0);
    issueDMA(srcA + 32, srcB0 + 32768, srcB1 + 32768, 1);

    const short* pA  = srcA  + 64;        // next: ks = 2 (strides: A 32, B 32768)
    const short* pB0 = srcB0 + 65536;
    const short* pB1 = srcB1 + 65536;

    int cur = 0;
    #pragma unroll 1
    for (int p = 0; p < 16; ++p) {
        // drain my wave's DMA(p), leave DMA(p+1) in flight; then sync waves
        if (p < 15) { asm volatile("s_waitcnt vmcnt(3)" ::: "memory"); }
        else        { asm volatile("s_waitcnt vmcnt(0)" ::: "memory"); }
        __builtin_amdgcn_s_barrier();
        if (p < 14) {
            int nb = cur + 2; if (nb >= 3) nb -= 3;
            issueDMA(pA, pB0, pB1, nb);      // overwrites buf read 3 phases ago
            pA += 32; pB0 += 32768; pB1 += 32768;
        }
        compute(cur);
        if (++cur == 3) cur = 0;
    }

    // ---- fused LSTM epilogue (lane-local: all 4 gates in acc[m][0..3]) ----
    const size_t HS = (size_t)NROWS * NUNITS;
    const int u = ut * 64 + q * 16 + lr;
    const float bi = bias[u],       bfg = bias[256 + u];
    const float bc = bias[512 + u], bo  = bias[768 + u];
    const float ppi = pi[u], ppf = pf[u], ppo = po[u];
    #pragma unroll
    for (int m = 0; m < 4; ++m) {
        #pragma unroll
        for (int r = 0; r < 4; ++r) {
            const int row = row0 + rh * 64 + m * 16 + hi * 4 + r;
            const size_t o = (size_t)row * NUNITS + u;
            const float cp = c_prev[o];
            float zi = acc[m][0][r] + bi  + ppi * cp;
            float zf = acc[m][1][r] + bfg + ppf * cp;
            float zc = acc[m][2][r] + bc;
            float zo = acc[m][3][r] + bo  + ppo * cp;
            float ig = 1.f / (1.f + __expf(-zi));
            float fg = 1.f / (1.f + __expf(-zf));
            float og = 1.f / (1.f + __expf(-zo));
            zc = fminf(fmaxf(zc, -30.f), 30.f);
            float e2 = __expf(2.f * zc);
            float chat = (e2 - 1.f) / (e2 + 1.f);
            float c  = fg * cp + ig * chat;
            float ccl = fminf(fmaxf(c, -30.f), 30.f);
            float e3 = __expf(2.f * ccl);
            float th = (e3 - 1.f) / (e3 + 1.f);
            float h  = og * th;
            out[o]          = h;
            out[HS + o]     = h;
            out[2 * HS + o] = c;
        }
    }
}

extern "C" void kernel_launch(void* const* d_in, const int* in_sizes, int n_in,
                              void* d_out, int out_size, void* d_ws, size_t ws_size,
                              hipStream_t stream) {
    const float* x  = (const float*)d_in[0];
    const float* h  = (const float*)d_in[1];
    const float* c  = (const float*)d_in[2];
    const float* W  = (const float*)d_in[3];
    const float* b  = (const float*)d_in[4];
    const float* pi = (const float*)d_in[5];
    const float* pf = (const float*)d_in[6];
    const float* po = (const float*)d_in[7];
    float* out = (float*)d_out;

    const size_t aws_bytes = (size_t)NROWS * KTOT * 2;   // 134,217,728
    short* Aws = (short*)d_ws;
    short* Wws = (short*)((char*)d_ws + aws_bytes);

    hipLaunchKernelGGL(convert_kernel, dim3(32768 + 2048), dim3(256), 0, stream,
                       x, h, W, Aws, Wws);
    hipLaunchKernelGGL(lstm_main_kernel, dim3(NROWS / BM * 4), dim3(THREADS), 0, stream,
                       c, b, pi, pf, po, Aws, Wws, out);
}